// Round 1
// baseline (10958.099 us; speedup 1.0000x reference)
//
#include <hip/hip_runtime.h>

#define T_LEN 1024
#define HID   128
#define G4    512
#define BCH   4
#define NWG   128

__device__ __forceinline__ float fsig(float v) {
  return __builtin_amdgcn_rcpf(1.0f + __expf(-v));
}
__device__ __forceinline__ float ftanh(float v) {
  float a = fabsf(v);
  float e = __expf(-2.0f * a);
  float t = (1.0f - e) * __builtin_amdgcn_rcpf(1.0f + e);
  return copysignf(t, v);
}
__device__ __forceinline__ float gact(float v, int gt) {
  return (gt == 2) ? ftanh(v) : fsig(v);
}

// [512][128] row-major -> [128][512] k-major, three matrices packed into ws
__global__ void __launch_bounds__(512) transpose_w(
    const float* __restrict__ w1, const float* __restrict__ w2,
    const float* __restrict__ w3, float* __restrict__ o) {
  int m = blockIdx.y;
  const float* src = (m == 0) ? w1 : (m == 1) ? w2 : w3;
  float* dst = o + (size_t)m * G4 * HID;
  int idx = blockIdx.x * 512 + threadIdx.x;  // 0..65535
  int j = idx >> 7;
  int k = idx & (HID - 1);
  dst[k * G4 + j] = src[idx];
}

__device__ __forceinline__ void store_out(const float4* h2buf, float wo0, float wo1,
                                          float bo, int tid, int b0,
                                          float* __restrict__ outp, int t) {
  // wave 0 only (tid < 64). h2buf[k] = {h2[b0..b3][k]}
  float4 ha = h2buf[tid];
  float4 hb = h2buf[tid + 64];
  float p0 = wo0 * ha.x + wo1 * hb.x;
  float p1 = wo0 * ha.y + wo1 * hb.y;
  float p2 = wo0 * ha.z + wo1 * hb.z;
  float p3 = wo0 * ha.w + wo1 * hb.w;
#pragma unroll
  for (int off = 1; off < 64; off <<= 1) {
    p0 += __shfl_xor(p0, off, 64);
    p1 += __shfl_xor(p1, off, 64);
    p2 += __shfl_xor(p2, off, 64);
    p3 += __shfl_xor(p3, off, 64);
  }
  if (tid < BCH) {
    float v = (tid == 0) ? p0 : (tid == 1) ? p1 : (tid == 2) ? p2 : p3;
    outp[(b0 + tid) * T_LEN + t] = v + bo;
  }
}

__global__ void __launch_bounds__(512) lstm_fused(
    const float* __restrict__ xin, const float* __restrict__ Wih1,
    const float* __restrict__ bih1, const float* __restrict__ bhh1,
    const float* __restrict__ Whh1, const float* __restrict__ Wih2,
    const float* __restrict__ Whh2, int sk, int sj,
    const float* __restrict__ bih2, const float* __restrict__ bhh2,
    const float* __restrict__ Wout, const float* __restrict__ bout,
    float* __restrict__ outp) {
  __shared__ float4 h1buf[HID];   // [k] -> 4 batches (batch-major float4)
  __shared__ float4 h2buf[HID];
  __shared__ float4 g1[G4];       // activated layer-1 gates, [row] -> 4 batches
  __shared__ float4 g2[G4];
  __shared__ float xb[2][BCH];    // double-buffered x(t)

  const int tid = threadIdx.x;
  const int b0 = blockIdx.x * BCH;
  const int gt = tid >> 7;        // 0:i 1:f 2:g 3:o

  float bias1 = bih1[tid] + bhh1[tid];
  float bias2 = bih2[tid] + bhh2[tid];
  float wi1 = Wih1[tid];
  float c1_0 = 0.f, c1_1 = 0.f, c1_2 = 0.f, c1_3 = 0.f;
  float c2_0 = 0.f, c2_1 = 0.f, c2_2 = 0.f, c2_3 = 0.f;
  float wo0 = 0.f, wo1 = 0.f, bo = 0.f;
  if (tid < 64) { wo0 = Wout[tid]; wo1 = Wout[tid + 64]; bo = bout[0]; }
  if (tid < HID) {
    h1buf[tid] = make_float4(0.f, 0.f, 0.f, 0.f);
    h2buf[tid] = make_float4(0.f, 0.f, 0.f, 0.f);
  }
  if (tid < BCH) xb[0][tid] = xin[(b0 + tid) * T_LEN];
  __syncthreads();

  const float* wp1  = Whh1 + tid * sj;
  const float* wp2  = Whh2 + tid * sj;
  const float* wpi2 = Wih2 + tid * sj;

  for (int t = 0; t < T_LEN; ++t) {
    // ---- phase 1: gates1 (K=128) + W_hh2*h2 half of gates2 (K=128) ----
    float xpref = 0.f;
    if ((tid & ~3) == 128 && (t + 1) < T_LEN)
      xpref = xin[(b0 + (tid & 3)) * T_LEN + t + 1];  // issue early, commit in phase 4

    if (tid < 64 && t > 0) store_out(h2buf, wo0, wo1, bo, tid, b0, outp, t - 1);

    float xv0 = xb[t & 1][0], xv1 = xb[t & 1][1];
    float xv2 = xb[t & 1][2], xv3 = xb[t & 1][3];
    float a10 = fmaf(wi1, xv0, bias1);
    float a11 = fmaf(wi1, xv1, bias1);
    float a12 = fmaf(wi1, xv2, bias1);
    float a13 = fmaf(wi1, xv3, bias1);
    float a20 = bias2, a21 = bias2, a22 = bias2, a23 = bias2;
#pragma unroll 8
    for (int k = 0; k < HID; ++k) {
      float w1 = wp1[k * sk];
      float w2 = wp2[k * sk];
      float4 hv1 = h1buf[k];
      float4 hv2 = h2buf[k];
      a10 = fmaf(w1, hv1.x, a10);
      a11 = fmaf(w1, hv1.y, a11);
      a12 = fmaf(w1, hv1.z, a12);
      a13 = fmaf(w1, hv1.w, a13);
      a20 = fmaf(w2, hv2.x, a20);
      a21 = fmaf(w2, hv2.y, a21);
      a22 = fmaf(w2, hv2.z, a22);
      a23 = fmaf(w2, hv2.w, a23);
    }
    float4 A1;
    A1.x = gact(a10, gt); A1.y = gact(a11, gt);
    A1.z = gact(a12, gt); A1.w = gact(a13, gt);
    g1[tid] = A1;
    __syncthreads();

    // ---- phase 2: c1/h1 update (unit threads) ----
    if (tid < HID) {
      float4 iv = g1[tid], fv = g1[tid + HID];
      float4 gv = g1[tid + 2 * HID], ov = g1[tid + 3 * HID];
      c1_0 = fmaf(fv.x, c1_0, iv.x * gv.x);
      c1_1 = fmaf(fv.y, c1_1, iv.y * gv.y);
      c1_2 = fmaf(fv.z, c1_2, iv.z * gv.z);
      c1_3 = fmaf(fv.w, c1_3, iv.w * gv.w);
      float4 h;
      h.x = ov.x * ftanh(c1_0);
      h.y = ov.y * ftanh(c1_1);
      h.z = ov.z * ftanh(c1_2);
      h.w = ov.w * ftanh(c1_3);
      h1buf[tid] = h;
    }
    __syncthreads();

    // ---- phase 3: gates2 += W_ih2 * h1(t) ----
#pragma unroll 8
    for (int k = 0; k < HID; ++k) {
      float w = wpi2[k * sk];
      float4 hv = h1buf[k];
      a20 = fmaf(w, hv.x, a20);
      a21 = fmaf(w, hv.y, a21);
      a22 = fmaf(w, hv.z, a22);
      a23 = fmaf(w, hv.w, a23);
    }
    float4 A2;
    A2.x = gact(a20, gt); A2.y = gact(a21, gt);
    A2.z = gact(a22, gt); A2.w = gact(a23, gt);
    g2[tid] = A2;
    __syncthreads();

    // ---- phase 4: c2/h2 update; commit x prefetch ----
    if (tid < HID) {
      float4 iv = g2[tid], fv = g2[tid + HID];
      float4 gv = g2[tid + 2 * HID], ov = g2[tid + 3 * HID];
      c2_0 = fmaf(fv.x, c2_0, iv.x * gv.x);
      c2_1 = fmaf(fv.y, c2_1, iv.y * gv.y);
      c2_2 = fmaf(fv.z, c2_2, iv.z * gv.z);
      c2_3 = fmaf(fv.w, c2_3, iv.w * gv.w);
      float4 h;
      h.x = ov.x * ftanh(c2_0);
      h.y = ov.y * ftanh(c2_1);
      h.z = ov.z * ftanh(c2_2);
      h.w = ov.w * ftanh(c2_3);
      h2buf[tid] = h;
    } else if ((tid & ~3) == 128 && (t + 1) < T_LEN) {
      xb[(t + 1) & 1][tid & 3] = xpref;
    }
    __syncthreads();
  }
  if (tid < 64) store_out(h2buf, wo0, wo1, bo, tid, b0, outp, T_LEN - 1);
}

extern "C" void kernel_launch(void* const* d_in, const int* in_sizes, int n_in,
                              void* d_out, int out_size, void* d_ws, size_t ws_size,
                              hipStream_t stream) {
  const float* xin  = (const float*)d_in[0];
  const float* Wih1 = (const float*)d_in[1];
  const float* Whh1 = (const float*)d_in[2];
  const float* bih1 = (const float*)d_in[3];
  const float* bhh1 = (const float*)d_in[4];
  const float* Wih2 = (const float*)d_in[5];
  const float* Whh2 = (const float*)d_in[6];
  const float* bih2 = (const float*)d_in[7];
  const float* bhh2 = (const float*)d_in[8];
  const float* Wout = (const float*)d_in[9];
  const float* bout = (const float*)d_in[10];
  float* outp = (float*)d_out;

  size_t need = (size_t)3 * G4 * HID * sizeof(float);
  if (ws_size >= need) {
    float* wt = (float*)d_ws;
    transpose_w<<<dim3(128, 3), 512, 0, stream>>>(Whh1, Wih2, Whh2, wt);
    lstm_fused<<<NWG, 512, 0, stream>>>(
        xin, Wih1, bih1, bhh1,
        wt, wt + (size_t)G4 * HID, wt + (size_t)2 * G4 * HID, G4, 1,
        bih2, bhh2, Wout, bout, outp);
  } else {
    // fallback: read original row-major weights (uncoalesced but correct)
    lstm_fused<<<NWG, 512, 0, stream>>>(
        xin, Wih1, bih1, bhh1,
        Whh1, Wih2, Whh2, 1, HID,
        bih2, bhh2, Wout, bout, outp);
  }
}